// Round 3
// baseline (981.018 us; speedup 1.0000x reference)
//
#include <hip/hip_runtime.h>
#include <math.h>

// ExpertGating: g = x @ gate_w^T + gate_b (16384x4096 @ 4096x64), top-8 desc
// (tie -> lowest idx), softmax. out: [0,131072) weights, [131072,262144) idx-as-float.
//
// Hybrid precision: fp32 GEMM (157 TF pipe) with fp64 promotion every 16 k-steps
// -> rigorous worst-case logit error 6.9e-5. Tokens whose top-9 adjacent gaps
// are all > 1e-3 provably rank identically to the fp64 reference; the rare
// borderline token (~2-3%) is recomputed in full fp64 by its block.
// R1 lesson: LDS bytes/MAC was the wall (328 us model vs 376 measured). Here w
// is read via wave-uniform scalar loads (L2-resident, 0 LDS bytes) and x costs
// 1 ds_read_b128 per 256 MACs.

#define NT 16384
#define HID 4096
#define NE 64
#define TOPK 8
#define BT 64          // tokens per block (lane <-> token)
#define CK 64          // K-chunk staged in LDS
#define NCH (HID / CK)
#define XS_S 68        // x LDS row stride (floats): 17 quads, odd -> conflict-free b128
#define LG_S 65        // logit LDS row stride (doubles)
#define MARGIN 1e-3    // 14x rigorous worst-case fp32-path error

__device__ __forceinline__ void scan_top(const double* row, double* vals, int* idxs, int np) {
    unsigned long long sel = 0ull;
    for (int kk = 0; kk < np; kk++) {
        double bv = -1e300;
        int bi = 0;
        for (int e = 0; e < NE; e++) {
            bool valid = !((sel >> e) & 1ull);
            double v = row[e];
            bool take = valid && (v > bv);   // strict > : lowest index wins ties
            bv = take ? v : bv;
            bi = take ? e : bi;
        }
        sel |= 1ull << bi;
        vals[kk] = bv;
        idxs[kk] = bi;
    }
}

__global__ __launch_bounds__(512, 2)
void gating_kernel(const float* __restrict__ x,
                   const float* __restrict__ gw,
                   const float* __restrict__ gb,
                   float* __restrict__ out) {
    __shared__ union {
        float  xs[BT * XS_S];      // 17408 B, alive during GEMM
        double lg[BT * LG_S];      // 33280 B, alive after GEMM
    } u;
    __shared__ double pp[NE * 9];  // fallback partials [e][slice], stride 9
    __shared__ int flags[BT];

    const int tid  = threadIdx.x;
    const int ln   = tid & 63;                                    // token within block
    const int wv   = __builtin_amdgcn_readfirstlane(tid >> 6);    // SGPR wave id
    const int eb   = wv * 8;                                      // this wave's experts
    const int tok0 = blockIdx.x * BT;

    // ---- prefetch chunk 0 (x tile 64 tok x 64 k = 4096 floats, 2 float4/thread)
    float4 px[2];
#pragma unroll
    for (int i = 0; i < 2; i++) {
        int idx = i * 512 + tid, r = idx >> 4, c = (idx & 15) << 2;
        px[i] = *(const float4*)(x + (size_t)(tok0 + r) * HID + c);
    }

    double dacc[8];
#pragma unroll
    for (int e = 0; e < 8; e++) dacc[e] = 0.0;

    for (int ch = 0; ch < NCH; ch++) {
        __syncthreads();
#pragma unroll
        for (int i = 0; i < 2; i++) {
            int idx = i * 512 + tid, r = idx >> 4, c = (idx & 15) << 2;
            *(float4*)(&u.xs[r * XS_S + c]) = px[i];
        }
        __syncthreads();
        if (ch + 1 < NCH) {
            const int k0n = (ch + 1) * CK;
#pragma unroll
            for (int i = 0; i < 2; i++) {
                int idx = i * 512 + tid, r = idx >> 4, c = (idx & 15) << 2;
                px[i] = *(const float4*)(x + (size_t)(tok0 + r) * HID + k0n + c);
            }
        }

        const float* xrow  = &u.xs[ln * XS_S];
        const float* wbase = gw + (size_t)eb * HID + ch * CK;   // uniform -> s_load
#pragma unroll
        for (int q = 0; q < 4; q++) {        // 16-k sub-chunks, fp64 promote each
            float f[8];
#pragma unroll
            for (int e = 0; e < 8; e++) f[e] = 0.f;
#pragma unroll
            for (int g = 0; g < 4; g++) {
                const int k = q * 16 + g * 4;
                float4 xv = *(const float4*)(xrow + k);
#pragma unroll
                for (int e = 0; e < 8; e++) {
                    float4 w4 = *(const float4*)(wbase + (size_t)e * HID + k);
                    f[e] = fmaf(xv.x, w4.x, f[e]);
                    f[e] = fmaf(xv.y, w4.y, f[e]);
                    f[e] = fmaf(xv.z, w4.z, f[e]);
                    f[e] = fmaf(xv.w, w4.w, f[e]);
                }
            }
#pragma unroll
            for (int e = 0; e < 8; e++) dacc[e] += (double)f[e];
        }
    }

    // ---- logits (fp64) to LDS: lane's token row, this wave's 8 experts
    __syncthreads();   // xs dead
    {
        double* lgrow = &u.lg[ln * LG_S + eb];
#pragma unroll
        for (int e = 0; e < 8; e++) lgrow[e] = dacc[e] + (double)gb[eb + e];
    }
    __syncthreads();

    // ---- wave 0: top-9 scan + margin flag (one lane per token)
    double vals[9];
    int idxs[9];
    int myflag = 0;
    if (wv == 0) {
        scan_top(&u.lg[ln * LG_S], vals, idxs, 9);
        double mg = 1e300;
#pragma unroll
        for (int kk = 0; kk < 8; kk++) {
            double g = vals[kk] - vals[kk + 1];
            mg = (g < mg) ? g : mg;
        }
        myflag = (mg < MARGIN) ? 1 : 0;
        flags[ln] = myflag;
    }
    __syncthreads();

    // ---- block-wide fp64 recompute for flagged tokens (rare)
    for (int t = 0; t < BT; t++) {
        if (flags[t]) {
            const int e  = tid & 63;
            const int sl = wv;                    // k-slice 0..7 (512 k each)
            const float* xr = x  + (size_t)(tok0 + t) * HID + sl * 512;
            const float* wr = gw + (size_t)e * HID + sl * 512;
            double p0 = 0., p1 = 0., p2 = 0., p3 = 0.;
            for (int kk = 0; kk < 512; kk += 4) {
                float4 a = *(const float4*)(xr + kk);
                float4 b = *(const float4*)(wr + kk);
                p0 = fma((double)a.x, (double)b.x, p0);
                p1 = fma((double)a.y, (double)b.y, p1);
                p2 = fma((double)a.z, (double)b.z, p2);
                p3 = fma((double)a.w, (double)b.w, p3);
            }
            pp[e * 9 + sl] = (p0 + p1) + (p2 + p3);
            __syncthreads();
            if (tid < 64) {
                double s = (double)gb[tid];
#pragma unroll
                for (int s2 = 0; s2 < 8; s2++) s += pp[tid * 9 + s2];
                u.lg[t * LG_S + tid] = s;
            }
            __syncthreads();
        }
    }

    // ---- wave 0: rescan flagged, softmax, write
    if (wv == 0) {
        if (myflag) scan_top(&u.lg[ln * LG_S], vals, idxs, 8);
        double mx = vals[0];
        float ex[TOPK], s = 0.f;
#pragma unroll
        for (int k = 0; k < TOPK; k++) {
            ex[k] = expf((float)(vals[k] - mx));
            s += ex[k];
        }
        float inv = 1.0f / s;
        float* ow = out;
        float* oi = out + NT * TOPK;
        int gt = tok0 + ln;
#pragma unroll
        for (int k = 0; k < TOPK; k++) {
            ow[gt * TOPK + k] = ex[k] * inv;
            oi[gt * TOPK + k] = (float)idxs[k];
        }
    }
}

extern "C" void kernel_launch(void* const* d_in, const int* in_sizes, int n_in,
                              void* d_out, int out_size, void* d_ws, size_t ws_size,
                              hipStream_t stream) {
    const float* x  = (const float*)d_in[0];
    const float* gw = (const float*)d_in[1];
    const float* gb = (const float*)d_in[2];
    float* out = (float*)d_out;

    dim3 grid(NT / BT);   // 256 blocks -> 1 block/CU, 8 waves/CU
    dim3 block(512);
    gating_kernel<<<grid, block, 0, stream>>>(x, gw, gb, out);
}

// Round 4
// 512.658 us; speedup vs baseline: 1.9136x; 1.9136x over previous
//
#include <hip/hip_runtime.h>
#include <math.h>

// ExpertGating: g = x @ gate_w^T + gate_b (16384x4096 @ 4096x64), top-8 desc
// (tie -> lowest idx), softmax. out: [0,131072) weights, [131072,262144) idx-as-float.
//
// bf16-split MFMA: x,w split into bf16 hi+lo (truncation; residual <= 2^-16).
// 4 passes (hh+hl+lh+ll) into one fp32 acc -> logit err RMS ~1e-5.
// Tokens with any top-9 adjacent gap < MARGIN (2.5e-4, ~20 sigma) get an exact
// fp64 recompute of candidate experts (lg >= 9th - MARGIN) by one wave.
// R3 lesson: never per-lane global loads in the K-loop -> both operands LDS-staged.

#define NT 16384
#define HID 4096
#define NE 64
#define TOPK 8
#define BT 32          // tokens per block
#define CK 64          // K-chunk
#define NCH (HID / CK)
#define SK 72          // LDS tile row stride (bf16 elems): 144 B rows, frag b128 conflict-free
#define LG_S 65
#define MARGIN 2.5e-4f

typedef __attribute__((ext_vector_type(8))) short bf16x8;
typedef __attribute__((ext_vector_type(4))) float f32x4;

__global__ __launch_bounds__(256, 2)
void gating_kernel(const float* __restrict__ x,
                   const float* __restrict__ gw,
                   const float* __restrict__ gb,
                   float* __restrict__ out) {
    __shared__ unsigned short sx_hi[BT * SK], sx_lo[BT * SK];   // 4608 B each
    __shared__ unsigned short sw_hi[NE * SK], sw_lo[NE * SK];   // 9216 B each
    __shared__ float lg[BT * LG_S];                             // 8320 B
    __shared__ float thr9s[BT];
    __shared__ int flags[BT], flist[BT], fcnt;

    const int tid  = threadIdx.x;
    const int ln   = tid & 63;
    const int wv   = __builtin_amdgcn_readfirstlane(tid >> 6);  // 0..3
    const int tok0 = blockIdx.x * BT;
    const int tb   = (wv & 1) * 16;    // wave token group
    const int eb   = (wv >> 1) * 32;   // wave expert half
    const int mr   = ln & 15;
    const int q    = ln >> 4;

    f32x4 acc0 = {0.f, 0.f, 0.f, 0.f};
    f32x4 acc1 = {0.f, 0.f, 0.f, 0.f};

    // ---- prefetch chunk 0
    float4 px[2], pw[4];
#pragma unroll
    for (int j = 0; j < 2; j++) {
        int fl = j * 256 + tid, r = fl >> 4, c = (fl & 15) << 2;
        px[j] = *(const float4*)(x + (size_t)(tok0 + r) * HID + c);
    }
#pragma unroll
    for (int j = 0; j < 4; j++) {
        int fl = j * 256 + tid, r = fl >> 4, c = (fl & 15) << 2;
        pw[j] = *(const float4*)(gw + (size_t)r * HID + c);
    }

    for (int ch = 0; ch < NCH; ch++) {
        __syncthreads();
        // ---- convert + store current chunk (truncation split: hi=top16 bits, lo=f-hi)
#pragma unroll
        for (int j = 0; j < 2; j++) {
            int fl = j * 256 + tid, r = fl >> 4, c = (fl & 15) << 2;
            float4 v = px[j];
            uint u0 = __float_as_uint(v.x), u1 = __float_as_uint(v.y);
            uint u2 = __float_as_uint(v.z), u3 = __float_as_uint(v.w);
            ushort4 hi = make_ushort4(u0 >> 16, u1 >> 16, u2 >> 16, u3 >> 16);
            float l0 = v.x - __uint_as_float(u0 & 0xFFFF0000u);
            float l1 = v.y - __uint_as_float(u1 & 0xFFFF0000u);
            float l2 = v.z - __uint_as_float(u2 & 0xFFFF0000u);
            float l3 = v.w - __uint_as_float(u3 & 0xFFFF0000u);
            ushort4 lo = make_ushort4(__float_as_uint(l0) >> 16, __float_as_uint(l1) >> 16,
                                      __float_as_uint(l2) >> 16, __float_as_uint(l3) >> 16);
            *(ushort4*)&sx_hi[r * SK + c] = hi;
            *(ushort4*)&sx_lo[r * SK + c] = lo;
        }
#pragma unroll
        for (int j = 0; j < 4; j++) {
            int fl = j * 256 + tid, r = fl >> 4, c = (fl & 15) << 2;
            float4 v = pw[j];
            uint u0 = __float_as_uint(v.x), u1 = __float_as_uint(v.y);
            uint u2 = __float_as_uint(v.z), u3 = __float_as_uint(v.w);
            ushort4 hi = make_ushort4(u0 >> 16, u1 >> 16, u2 >> 16, u3 >> 16);
            float l0 = v.x - __uint_as_float(u0 & 0xFFFF0000u);
            float l1 = v.y - __uint_as_float(u1 & 0xFFFF0000u);
            float l2 = v.z - __uint_as_float(u2 & 0xFFFF0000u);
            float l3 = v.w - __uint_as_float(u3 & 0xFFFF0000u);
            ushort4 lo = make_ushort4(__float_as_uint(l0) >> 16, __float_as_uint(l1) >> 16,
                                      __float_as_uint(l2) >> 16, __float_as_uint(l3) >> 16);
            *(ushort4*)&sw_hi[r * SK + c] = hi;
            *(ushort4*)&sw_lo[r * SK + c] = lo;
        }
        __syncthreads();

        if (ch + 1 < NCH) {
            const int k0 = (ch + 1) * CK;
#pragma unroll
            for (int j = 0; j < 2; j++) {
                int fl = j * 256 + tid, r = fl >> 4, c = (fl & 15) << 2;
                px[j] = *(const float4*)(x + (size_t)(tok0 + r) * HID + k0 + c);
            }
#pragma unroll
            for (int j = 0; j < 4; j++) {
                int fl = j * 256 + tid, r = fl >> 4, c = (fl & 15) << 2;
                pw[j] = *(const float4*)(gw + (size_t)r * HID + k0 + c);
            }
        }

        // ---- MFMA: 2 K=32 steps x 2 expert tiles x 4 split passes
        const int aof  = (tb + mr) * SK + q * 8;
        const int b0of = (eb + mr) * SK + q * 8;
        const int b1of = (eb + 16 + mr) * SK + q * 8;
#pragma unroll
        for (int s = 0; s < 2; s++) {
            const int o = s * 32;
            bf16x8 ah  = *(const bf16x8*)&sx_hi[aof + o];
            bf16x8 al  = *(const bf16x8*)&sx_lo[aof + o];
            bf16x8 b0h = *(const bf16x8*)&sw_hi[b0of + o];
            bf16x8 b0l = *(const bf16x8*)&sw_lo[b0of + o];
            bf16x8 b1h = *(const bf16x8*)&sw_hi[b1of + o];
            bf16x8 b1l = *(const bf16x8*)&sw_lo[b1of + o];
            acc0 = __builtin_amdgcn_mfma_f32_16x16x32_bf16(ah, b0h, acc0, 0, 0, 0);
            acc1 = __builtin_amdgcn_mfma_f32_16x16x32_bf16(ah, b1h, acc1, 0, 0, 0);
            acc0 = __builtin_amdgcn_mfma_f32_16x16x32_bf16(ah, b0l, acc0, 0, 0, 0);
            acc1 = __builtin_amdgcn_mfma_f32_16x16x32_bf16(ah, b1l, acc1, 0, 0, 0);
            acc0 = __builtin_amdgcn_mfma_f32_16x16x32_bf16(al, b0h, acc0, 0, 0, 0);
            acc1 = __builtin_amdgcn_mfma_f32_16x16x32_bf16(al, b1h, acc1, 0, 0, 0);
            acc0 = __builtin_amdgcn_mfma_f32_16x16x32_bf16(al, b0l, acc0, 0, 0, 0);
            acc1 = __builtin_amdgcn_mfma_f32_16x16x32_bf16(al, b1l, acc1, 0, 0, 0);
        }
    }

    // ---- epilogue: C/D layout row=(ln>>4)*4+reg (token), col=ln&15 (expert)
    __syncthreads();
    {
        int e0 = eb + mr, e1 = eb + 16 + mr;
        float bb0 = gb[e0], bb1 = gb[e1];
#pragma unroll
        for (int i = 0; i < 4; i++) {
            int t = tb + q * 4 + i;
            lg[t * LG_S + e0] = acc0[i] + bb0;
            lg[t * LG_S + e1] = acc1[i] + bb1;
        }
    }
    if (tid == 0) fcnt = 0;
    __syncthreads();

    // ---- top-9 scan + margin flag: lanes 0..7 per wave, one token each
    float vals[9];
    int idxs[9];
    int myflag = 0;
    if (ln < 8) {
        int t = wv * 8 + ln;
        const float* row = &lg[t * LG_S];
        unsigned long long sel = 0ull;
#pragma unroll
        for (int kk = 0; kk < 9; kk++) {
            float bv = -1e30f;
            int bi = 0;
            for (int e = 0; e < NE; e++) {
                bool valid = !((sel >> e) & 1ull);
                float v = row[e];
                bool take = valid && (v > bv);
                bv = take ? v : bv;
                bi = take ? e : bi;
            }
            sel |= 1ull << bi;
            vals[kk] = bv;
            idxs[kk] = bi;
        }
        float mg = 1e30f;
#pragma unroll
        for (int kk = 0; kk < 8; kk++) {
            float g = vals[kk] - vals[kk + 1];
            mg = (g < mg) ? g : mg;
        }
        myflag = (mg < MARGIN) ? 1 : 0;
        flags[t] = myflag;
        thr9s[t] = vals[8];
        if (!myflag) {
            float mx = vals[0], ex[TOPK], s = 0.f;
#pragma unroll
            for (int k = 0; k < TOPK; k++) { ex[k] = expf(vals[k] - mx); s += ex[k]; }
            float inv = 1.0f / s;
            int gt = tok0 + t;
#pragma unroll
            for (int k = 0; k < TOPK; k++) {
                out[gt * TOPK + k] = ex[k] * inv;
                out[NT * TOPK + gt * TOPK + k] = (float)idxs[k];
            }
        }
    }
    __syncthreads();

    if (tid == 0) {
        int n = 0;
        for (int t = 0; t < BT; t++) if (flags[t]) flist[n++] = t;
        fcnt = n;
    }
    __syncthreads();

    // ---- fp64 fallback: one wave per flagged token, candidate experts only
    for (int i = wv; i < fcnt; i += 4) {
        int t = flist[i];
        bool active = lg[t * LG_S + ln] >= thr9s[t] - MARGIN;
        double p0 = 0., p1 = 0., p2 = 0., p3 = 0.;
        if (active) {
            const float* xr = x + (size_t)(tok0 + t) * HID;
            const float* wr = gw + (size_t)ln * HID;
            for (int k = 0; k < HID; k += 4) {
                float4 a = *(const float4*)(xr + k);
                float4 b = *(const float4*)(wr + k);
                p0 = fma((double)a.x, (double)b.x, p0);
                p1 = fma((double)a.y, (double)b.y, p1);
                p2 = fma((double)a.z, (double)b.z, p2);
                p3 = fma((double)a.w, (double)b.w, p3);
            }
        }
        double base = active ? ((p0 + p1) + (p2 + p3) + (double)gb[ln]) : -1e18;
        double mv[TOPK];
        int mi[TOPK];
#pragma unroll
        for (int k = 0; k < TOPK; k++) {
            double v = base;
            int ii = ln;
#pragma unroll
            for (int off = 32; off >= 1; off >>= 1) {
                double ov = __shfl_xor(v, off);
                int oi = __shfl_xor(ii, off);
                if (ov > v || (ov == v && oi < ii)) { v = ov; ii = oi; }
            }
            mv[k] = v;
            mi[k] = ii;
            if (ln == ii) base = -1e18;
        }
        if (ln == 0) {
            double mx = mv[0];
            float ex[TOPK], s = 0.f;
#pragma unroll
            for (int k = 0; k < TOPK; k++) { ex[k] = expf((float)(mv[k] - mx)); s += ex[k]; }
            float inv = 1.0f / s;
            int gt = tok0 + t;
#pragma unroll
            for (int k = 0; k < TOPK; k++) {
                out[gt * TOPK + k] = ex[k] * inv;
                out[NT * TOPK + gt * TOPK + k] = (float)mi[k];
            }
        }
    }
}

extern "C" void kernel_launch(void* const* d_in, const int* in_sizes, int n_in,
                              void* d_out, int out_size, void* d_ws, size_t ws_size,
                              hipStream_t stream) {
    const float* x  = (const float*)d_in[0];
    const float* gw = (const float*)d_in[1];
    const float* gb = (const float*)d_in[2];
    float* out = (float*)d_out;

    dim3 grid(NT / BT);   // 512 blocks -> 2 blocks/CU
    dim3 block(256);
    gating_kernel<<<grid, block, 0, stream>>>(x, gw, gb, out);
}